// Round 1
// 6577.180 us; speedup vs baseline: 1.2121x; 1.2121x over previous
//
#include <hip/hip_runtime.h>
#include <cstdint>
#include <cstddef>

// MessagePassing (SCNN-style): 4 sequential directional scans.
// B=16 C=128 H=72 W=200 K=9 pad=4, fp32 in/out.
//
// Round-2: MFMA engine (split-fp16, 3-term: Whi*Ahi + Whi*Alo + Wlo*Ahi,
// rel err ~2^-22 -> absmax should match fp32 baseline 0.25).
//  - block = (b, 16-pos chunk); wave = 16-co M-tile (8 waves = 128 co).
//  - Whi A-frags persistent in VGPRs (36 k-tiles x 4 VGPR = 144), loaded once
//    from pre-repacked fragment array; Wlo streamed from L2 (address-stable).
//  - K order dk-major (k = dk*128 + ci) -> B-frag = one aligned ds_read_b128
//    from [pos][ci] fp16 planes (row stride 68 u32 -> 2-way conflicts = free).
//  - Sync: per-(b,row,chunk) flags; consumer waits only on 2 neighbor chunks
//    (halo +-4 < 16). H: 208 blocks, W: 80 -> co-resident, no deadlock.
//
// Round-3: kill the per-step L2 cache-maintenance thrash.
//  - OLD: acquire flag loads (-> buffer_inv, L2-wide invalidate) + release
//    flag store (-> buffer_wbl2, L2-wide writeback) EVERY step by EVERY block
//    (26 blocks/XCD on H pass) wiped the shared per-XCD L2 -> wlo weight
//    stream (288 KB/block/step) + window + cur all missed to MALL/HBM
//    latency. Counters: MfmaUtil 3.8%, VALUBusy 1.8%, HBM 1.1% = pure
//    latency stall.
//  - NEW: all cross-block data (epilogue stores, window reads, cur reads)
//    use RELAXED agent-scope atomics -> per-op sc0/sc1 bypass straight to
//    the MALL coherence point, NO cache-wide ops, XCD-placement-independent.
//    Flag store relaxed: producer's atomic stores are write-through and the
//    pre-flag __syncthreads drains vmcnt(0) -> globally visible before flag.
//    Consumer: control-dependent spin + __syncthreads (compiler mem fence)
//    orders window loads after flag observation. Weights stay normally
//    cached -> wlo L2-resident again.

#define B_ 16
#define C_ 128
#define H_ 72
#define W_ 200
#define KW 9
#define NTOT (B_ * C_ * H_ * W_)

using f16x8 = _Float16 __attribute__((ext_vector_type(8)));
using f32x4 = float __attribute__((ext_vector_type(4)));

__device__ __forceinline__ unsigned pack_h2(_Float16 lo, _Float16 hi) {
  unsigned short a = __builtin_bit_cast(unsigned short, lo);
  unsigned short b = __builtin_bit_cast(unsigned short, hi);
  return (unsigned)a | ((unsigned)b << 16);
}

// device-coherent (MALL) access, no cache-wide maintenance ops
__device__ __forceinline__ float dev_load(const float* p) {
  return __hip_atomic_load(p, __ATOMIC_RELAXED, __HIP_MEMORY_SCOPE_AGENT);
}
__device__ __forceinline__ void dev_store(float* p, float v) {
  __hip_atomic_store(p, v, __ATOMIC_RELAXED, __HIP_MEMORY_SCOPE_AGENT);
}

// ---------------- copy x -> out ----------------
__global__ void copy_f4(const float4* __restrict__ src, float4* __restrict__ dst, int n4) {
  int i = blockIdx.x * blockDim.x + threadIdx.x;
  const int stride = gridDim.x * blockDim.x;
  for (; i < n4; i += stride) dst[i] = src[i];
}

// ---------------- transpose last two dims ----------------
template <int SH, int SW>
__global__ void transpose_hw(const float* __restrict__ src, float* __restrict__ dst) {
  __shared__ float t[32][33];
  const size_t base = (size_t)blockIdx.z * SH * SW;
  const int x = blockIdx.x * 32 + threadIdx.x;
#pragma unroll
  for (int j = 0; j < 4; ++j) {
    const int y = blockIdx.y * 32 + threadIdx.y + j * 8;
    if (y < SH && x < SW) t[threadIdx.y + j * 8][threadIdx.x] = src[base + (size_t)y * SW + x];
  }
  __syncthreads();
  const int x2 = blockIdx.y * 32 + threadIdx.x;
#pragma unroll
  for (int j = 0; j < 4; ++j) {
    const int y2 = blockIdx.x * 32 + threadIdx.y + j * 8;
    if (y2 < SW && x2 < SH) dst[base + (size_t)y2 * SH + x2] = t[threadIdx.x][threadIdx.y + j * 8];
  }
}

// ---------------- weight repack: wgt[co][ci][dk] -> MFMA A-frag order ----------------
// frag index: [cot(8)][t(36)][lane(64)] f16x8; lane: m=lane&15 (co), q=lane>>4;
// element j <-> k = t*32 + q*8 + j, k = dk*128 + ci (dk = t>>2, ci = (t&3)*32 + q*8 + j)
__global__ void repack_w(const float* __restrict__ wgt, f16x8* __restrict__ whi,
                         f16x8* __restrict__ wlo) {
  const int blk = blockIdx.x;  // cot*36 + t
  const int cot = blk / 36, t = blk % 36;
  const int lane = threadIdx.x;
  const int n = lane & 15, q = lane >> 4;
  const int co = cot * 16 + n, dk = t >> 2, ci0 = (t & 3) * 32 + q * 8;
  f16x8 h, l;
#pragma unroll
  for (int j = 0; j < 8; ++j) {
    const float w = wgt[((size_t)co * C_ + ci0 + j) * KW + dk];
    const _Float16 hh = (_Float16)w;
    h[j] = hh;
    l[j] = (_Float16)(w - (float)hh);
  }
  whi[(size_t)blk * 64 + lane] = h;
  wlo[(size_t)blk * 64 + lane] = l;
}

// ---------------- MFMA scan pass ----------------
// data[b][c][RDIM][WDIM]; scan RDIM rows; conv (K=9,pad4) over contiguous WDIM.
// grid = 16*NCH blocks: b = bx&15, chunk jc = bx>>4 (16 positions).
template <int RDIM, int WDIM, int NCH>
__global__ __launch_bounds__(512, 1) void pass_mfma(float* __restrict__ data,
                                                    const f16x8* __restrict__ whi,
                                                    const f16x8* __restrict__ wlo,
                                                    unsigned* flags, const int dir) {
  constexpr int RW = RDIM * WDIM;
  __shared__ float win[128 * 25];  // natural [ci][wi(24)+1pad]
  __shared__ unsigned fh[24 * 68]; // [wi][ci-pair(64)] packed fp16 hi, stride 68
  __shared__ unsigned fl[24 * 68]; // lo plane

  const int tid = threadIdx.x;
  const int wave = tid >> 6, lane = tid & 63;
  const int n = lane & 15, q = lane >> 4;
  const int b = blockIdx.x & 15, jc = blockIdx.x >> 4;
  const int pos_base = jc * 16;
  const size_t bbase = (size_t)b * C_ * RW;

  // persistent A-frags (Whi) in VGPRs: 36 x 4 VGPR
  f16x8 ahi[36];
#pragma unroll
  for (int t = 0; t < 36; ++t) ahi[t] = whi[(size_t)(wave * 36 + t) * 64 + lane];
  const f16x8* wloL = wlo + (size_t)wave * 36 * 64 + lane;

  for (int s = 1; s < RDIM; ++s) {
    const int r = (dir > 0) ? s : (RDIM - 1 - s);
    const int rp = r - dir;  // producer row

    // preload current row r (written only by this block, later this step) --
    // issue BEFORE the flag spin so the MALL latency hides under the wait.
    const int pos = pos_base + n;
    float cur[4];
#pragma unroll
    for (int reg = 0; reg < 4; ++reg) {
      const int co = wave * 16 + q * 4 + reg;
      cur[reg] =
          (pos < WDIM) ? dev_load(&data[bbase + (size_t)co * RW + (size_t)r * WDIM + pos]) : 0.f;
    }

    if (s > 1 && tid < 2) {
      const int jn = jc + (tid ? 1 : -1);
      if (jn >= 0 && jn < NCH) {
        unsigned* f = &flags[((size_t)b * RDIM + rp) * NCH + jn];
        while (__hip_atomic_load(f, __ATOMIC_RELAXED, __HIP_MEMORY_SCOPE_AGENT) == 0u)
          __builtin_amdgcn_s_sleep(1);
        // no ACQUIRE fence: relaxed spin + __syncthreads (compiler memory
        // fence) + control dependence order the window loads below; data was
        // pushed to the coherence point by the producer before its flag store.
      }
    }
    __syncthreads();

    // phase 1: global row rp window [pos_base-4, pos_base+20) -> win
    // (device-coherent loads: rp was written by neighbors via dev_store)
#pragma unroll
    for (int i = 0; i < 6; ++i) {
      const int idx = tid + 512 * i;  // 3072 = 128ci * 24wi
      const int ci = idx / 24, wi = idx - ci * 24;
      const int p = pos_base - 4 + wi;
      float v = 0.f;
      if (p >= 0 && p < WDIM) v = dev_load(&data[bbase + (size_t)ci * RW + (size_t)rp * WDIM + p]);
      win[ci * 25 + wi] = v;
    }
    __syncthreads();

    // phase 2: transpose + split fp32 -> fp16 hi/lo planes [wi][ci]
#pragma unroll
    for (int i = 0; i < 3; ++i) {
      const int idx = tid + 512 * i;  // 1536 = 24wi * 64 ci-pairs
      const int wi = idx >> 6, c2 = idx & 63;
      const float x0 = win[(2 * c2) * 25 + wi];
      const float x1 = win[(2 * c2 + 1) * 25 + wi];
      const _Float16 h0 = (_Float16)x0, h1 = (_Float16)x1;
      const _Float16 l0 = (_Float16)(x0 - (float)h0), l1 = (_Float16)(x1 - (float)h1);
      fh[wi * 68 + c2] = pack_h2(h0, h1);
      fl[wi * 68 + c2] = pack_h2(l0, l1);
    }
    __syncthreads();

    // MFMA: D[co16 x pos16], K = 1152 (36 k-tiles), 3-term split
    f32x4 aA = {0.f, 0.f, 0.f, 0.f}, aB = {0.f, 0.f, 0.f, 0.f}, aC = {0.f, 0.f, 0.f, 0.f};
#pragma unroll
    for (int t = 0; t < 36; ++t) {
      const int dk = t >> 2;
      const int off = (n + dk) * 68 + (t & 3) * 16 + q * 4;  // u32 idx, 16B-aligned
      const f16x8 bh = *(const f16x8*)&fh[off];
      const f16x8 bl = *(const f16x8*)&fl[off];
      const f16x8 al = wloL[(size_t)t * 64];
      aA = __builtin_amdgcn_mfma_f32_16x16x32_f16(ahi[t], bh, aA, 0, 0, 0);
      aB = __builtin_amdgcn_mfma_f32_16x16x32_f16(ahi[t], bl, aB, 0, 0, 0);
      aC = __builtin_amdgcn_mfma_f32_16x16x32_f16(al, bh, aC, 0, 0, 0);
    }

    // epilogue: C/D layout col=lane&15 (pos), row=q*4+reg (co-within-tile).
    // device-coherent stores -> visible at MALL once vmcnt-acked (no wbl2).
    if (pos < WDIM) {
#pragma unroll
      for (int reg = 0; reg < 4; ++reg) {
        const int co = wave * 16 + q * 4 + reg;
        const float v = aA[reg] + aB[reg] + aC[reg];
        dev_store(&data[bbase + (size_t)co * RW + (size_t)r * WDIM + pos],
                  cur[reg] + fmaxf(v, 0.f));
      }
    }
    __syncthreads();  // vmcnt(0) drain before s_barrier -> stores visible
    if (tid == 0)
      __hip_atomic_store(&flags[((size_t)b * RDIM + r) * NCH + jc], 1u, __ATOMIC_RELAXED,
                         __HIP_MEMORY_SCOPE_AGENT);
  }
}

extern "C" void kernel_launch(void* const* d_in, const int* in_sizes, int n_in, void* d_out,
                              int out_size, void* d_ws, size_t ws_size, hipStream_t stream) {
  const float* x = (const float*)d_in[0];
  const float* w_down = (const float*)d_in[1];
  const float* w_up = (const float*)d_in[2];
  const float* w_right = (const float*)d_in[3];
  const float* w_left = (const float*)d_in[4];
  float* out = (float*)d_out;

  // ---- ws layout ----
  // [0, 256K):        flags (memset 0)
  // [256K, 256K+8*294912): weight frag planes (hi,lo) x 4 passes
  // [2,621,440, ...): transpose scratch T if it fits, else reuse d_in[0]
  unsigned* flags = (unsigned*)d_ws;
  unsigned* f_down = flags;                      // 72*13*16 = 14976
  unsigned* f_up = f_down + H_ * 13 * B_;        // 14976
  unsigned* f_right = f_up + H_ * 13 * B_;       // 200*5*16 = 16000
  unsigned* f_left = f_right + W_ * 5 * B_;      // 16000
  hipMemsetAsync(d_ws, 0, 262144, stream);

  const size_t PLANE = (size_t)8 * 36 * 64;  // f16x8 elements per plane = 294912 B
  f16x8* wf = (f16x8*)((char*)d_ws + 262144);
  f16x8* whi_d = wf + 0 * PLANE;
  f16x8* wlo_d = wf + 1 * PLANE;
  f16x8* whi_u = wf + 2 * PLANE;
  f16x8* wlo_u = wf + 3 * PLANE;
  f16x8* whi_r = wf + 4 * PLANE;
  f16x8* wlo_r = wf + 5 * PLANE;
  f16x8* whi_l = wf + 6 * PLANE;
  f16x8* wlo_l = wf + 7 * PLANE;

  const size_t toff = 262144 + 8 * PLANE * sizeof(f16x8);
  const size_t tbytes = (size_t)NTOT * sizeof(float);
  float* T = (ws_size >= toff + tbytes) ? (float*)((char*)d_ws + toff) : (float*)d_in[0];

  // weight repack (one-time per launch)
  repack_w<<<288, 64, 0, stream>>>(w_down, whi_d, wlo_d);
  repack_w<<<288, 64, 0, stream>>>(w_up, whi_u, wlo_u);
  repack_w<<<288, 64, 0, stream>>>(w_right, whi_r, wlo_r);
  repack_w<<<288, 64, 0, stream>>>(w_left, whi_l, wlo_l);

  // out = x
  copy_f4<<<1024, 256, 0, stream>>>((const float4*)x, (float4*)out, NTOT / 4);

  // down/up: scan h (RDIM=72), conv over w (WDIM=200, 13 chunks) -> 208 blocks
  pass_mfma<H_, W_, 13><<<16 * 13, 512, 0, stream>>>(out, whi_d, wlo_d, f_down, +1);
  pass_mfma<H_, W_, 13><<<16 * 13, 512, 0, stream>>>(out, whi_u, wlo_u, f_up, -1);

  // transpose [b,c,h,w] -> [b,c,w,h]
  {
    dim3 g((W_ + 31) / 32, (H_ + 31) / 32, B_ * C_);
    transpose_hw<H_, W_><<<g, dim3(32, 8), 0, stream>>>(out, T);
  }

  // right/left: scan w (RDIM=200), conv over h (WDIM=72, 5 chunks) -> 80 blocks
  pass_mfma<W_, H_, 5><<<16 * 5, 512, 0, stream>>>(T, whi_r, wlo_r, f_right, +1);
  pass_mfma<W_, H_, 5><<<16 * 5, 512, 0, stream>>>(T, whi_l, wlo_l, f_left, -1);

  // transpose back
  {
    dim3 g((H_ + 31) / 32, (W_ + 31) / 32, B_ * C_);
    transpose_hw<W_, H_><<<g, dim3(32, 8), 0, stream>>>(T, out);
  }
}